// Round 15
// baseline (3027.318 us; speedup 1.0000x reference)
//
#include <hip/hip_runtime.h>
#include <math.h>

#define TT 32
#define MAXREC 8
#define NBLK 128
#define NTHR 512

// workspace byte offsets
#define OFF_FINAL  0u          // 2 x 128 u64 tagged finals (parity buffers) = 2048
#define OFF_ESQ    4096u       // 8192 f32 exact |e|^2 = 32768
#define OFF_RST    36864u      // 128*4 f32
#define OFF_OUTHB  40960u      // 4096*128 bf16 = 1048576
#define OFF_WB     1089536u    // 2 MB: vqeH f16 (main) then dWb bf16 (k_dec)

#define IDXM 0x1FFFu
#define LOGN 33554432u        // 128*32*8192
#define TWO_PI_F 6.283185307179586f

typedef float f32x4 __attribute__((ext_vector_type(4)));
typedef short bf16x8 __attribute__((ext_vector_type(8)));
typedef _Float16 h2 __attribute__((ext_vector_type(2)));
typedef unsigned long long u64;

__device__ __forceinline__ float wredsum(float v) {
#pragma unroll
  for (int m = 32; m > 0; m >>= 1) v += __shfl_xor(v, m);
  return v;
}
// monotone float->u32 + 13-bit idx: u64-min == (min dist, then min idx)
__device__ __forceinline__ u64 packkey(float d, unsigned c) {
  unsigned u = __float_as_uint(d);
  u = (u & 0x80000000u) ? ~u : (u | 0x80000000u);
  return ((u64)u << 32) | c;
}
__device__ __forceinline__ float unpackd2(u64 key) {
  unsigned hi = (unsigned)(key >> 32);
  unsigned orig = (hi & 0x80000000u) ? (hi & 0x7fffffffu) : ~hi;
  return __uint_as_float(orig);
}
__device__ __forceinline__ unsigned short f2bf(float f) {
  unsigned u = __float_as_uint(f);
  unsigned r = (u >> 16) & 1u;
  u += 0x7fffu + r;
  return (unsigned short)(u >> 16);
}
__device__ __forceinline__ h2 bch2(unsigned u) { return __builtin_bit_cast(h2, u); }

#if __has_builtin(__builtin_amdgcn_fdot2)
#define FDOT2(a, b, c) __builtin_amdgcn_fdot2((a), (b), (c), false)
#else
#define FDOT2(a, b, c) fmaf((float)(a).x, (float)(b).x, fmaf((float)(a).y, (float)(b).y, (c)))
#endif

// ---- coherent (cross-XCD) accesses: finals only ----
__device__ __forceinline__ u64 ld_coh64(const u64* p) {
  u64 v;
  asm volatile("global_load_dwordx2 %0, %1, off sc0 sc1\n\ts_waitcnt vmcnt(0)"
               : "=&v"(v) : "v"(p) : "memory");
  return v;
}
__device__ __forceinline__ void st_coh64(u64* p, u64 v) {
  asm volatile("global_store_dwordx2 %0, %1, off sc0 sc1\n\ts_waitcnt vmcnt(0)"
               :: "v"(p), "v"(v) : "memory");
}

__global__ __launch_bounds__(256) void sacrsn_init(char* __restrict__ ws) {
  u64* fin = (u64*)(ws + OFF_FINAL);
  fin[threadIdx.x] = 0ull;   // 256 = both parity buffers
}

// vq_emb f32 -> f16 (WB) + exact esq
__global__ __launch_bounds__(256) void k_prepv(const float* __restrict__ vqe,
                                               char* __restrict__ ws) {
  _Float16* vqeH = (_Float16*)(ws + OFF_WB);
  float* esqG = (float*)(ws + OFF_ESQ);
  const int i = (blockIdx.x * 256 + threadIdx.x) * 4;
  float4 v = *(const float4*)(vqe + i);
  h2 lo = {(_Float16)v.x, (_Float16)v.y};
  h2 hi = {(_Float16)v.z, (_Float16)v.w};
  *(h2*)(vqeH + i) = lo;
  *(h2*)(vqeH + i + 2) = hi;
  if (blockIdx.x < 32) {
    const int c = blockIdx.x * 256 + threadIdx.x;
    const float4* e = (const float4*)(vqe + ((size_t)c << 7));
    float s = 0.f;
#pragma unroll 8
    for (int k4 = 0; k4 < 32; ++k4) {
      float4 q = e[k4];
      s = fmaf(q.x, q.x, fmaf(q.y, q.y, fmaf(q.z, q.z, fmaf(q.w, q.w, s))));
    }
    esqG[c] = s;
  }
}

// dec_W f32 -> bf16 (WB), runs AFTER main
__global__ __launch_bounds__(256) void k_prepd(const float* __restrict__ dW,
                                               char* __restrict__ ws) {
  unsigned short* dWb = (unsigned short*)(ws + OFF_WB);
  const int i = (blockIdx.x * 256 + threadIdx.x) * 4;
  float4 v = *(const float4*)(dW + i);
  ushort4 o;
  o.x = f2bf(v.x); o.y = f2bf(v.y); o.z = f2bf(v.z); o.w = f2bf(v.w);
  *(ushort4*)(dWb + i) = o;
}

__global__ __launch_bounds__(NTHR) void sacrsn_main(
    const int* __restrict__ x_seq, const float* __restrict__ enc,
    const float* __restrict__ vqe,
    const float* __restrict__ nrg, const float* __restrict__ nrb,
    const float* __restrict__ nig, const float* __restrict__ nib,
    const float* __restrict__ qWr, const float* __restrict__ qbr,
    const float* __restrict__ qWi, const float* __restrict__ qbi,
    const float* __restrict__ gtw, const float* __restrict__ gtb,
    const float* __restrict__ aW, const float* __restrict__ ab,
    const float* __restrict__ hbp, const float* __restrict__ igp,
    float* __restrict__ dout, char* __restrict__ ws)
{
  u64* finalA = (u64*)(ws + OFF_FINAL);                 // [parity][128]
  const float* esqG = (const float*)(ws + OFF_ESQ);
  const _Float16* vqeH = (const _Float16*)(ws + OFF_WB);
  unsigned short* outhB = (unsigned short*)(ws + OFF_OUTHB);
  float* rst = (float*)(ws + OFF_RST);

  const int tid = threadIdx.x;
  const int wv = tid >> 6, ln = tid & 63;
  const int blk = blockIdx.x;                           // = row

  // ---- LDS ----
  __shared__ float memLr[32 * 65];
  __shared__ float memLi[32 * 65];
  __shared__ __align__(16) float zfmL[128];
  __shared__ __align__(16) unsigned zh16L[64];          // z as packed f16 pairs
  __shared__ float gwrowL[128], pangL[64], zqL[128];
  __shared__ float qkL[6][64], simL[32], attnL[32], mrL[64], miL[64];
  __shared__ unsigned idxL[128] __attribute__((aligned(16)));
  __shared__ u64 key128L[128];
  __shared__ float arbWL[3 * 128];
  __shared__ float scalL[8], entpL[2], vqpL[2], wsumL[2], z2pL[2];
  __shared__ float accL[4], totL[4];
  __shared__ float dmeanS, z2S, szS;
  __shared__ unsigned iiS;
  __shared__ u64 actM[2], actN[2];
  __shared__ float LredL[8];
  __shared__ unsigned candCodeL[1024];
  __shared__ unsigned candCountL;
  __shared__ u64 koutL[1024];

  const float alpha = 1.0f / (1.0f + expf(-igp[0]));
  const float onema = 1.0f - alpha;
  const float hbias = log1pf(expf(hbp[0]));
  const float gtb0 = gtb[0];

  float lnG = 0.0f, lnB = 0.0f, gtwv = 0.0f;
  if (tid < 64) { lnG = nrg[tid]; lnB = nrb[tid]; }
  else if (tid < 128) { lnG = nig[tid - 64]; lnB = nib[tid - 64]; }
  if (tid < 128) gtwv = gtw[tid];
  for (int i = tid; i < 32 * 65; i += NTHR) { memLr[i] = 0.0f; memLi[i] = 0.0f; }
  if (tid < 4) { totL[tid] = 0.0f; accL[tid] = 0.0f; }
  if (tid < 2) actM[tid] = ~0ull;
  if (tid == 0) candCountL = 0u;
  for (int i = tid; i < 384; i += NTHR) arbWL[i] = aW[i];
  {
    int tok = x_seq[blk * TT];
    if (tid < 128) gwrowL[tid] = onema * enc[((size_t)tok << 7) + tid];
  }
  __syncthreads();
  if (tid < 64) pangL[tid] = atan2f(gwrowL[64 + tid], gwrowL[tid]);
  if (tid < 128) {
    float val = gwrowL[tid];
    float mu = wredsum(val) * 0.015625f;
    float xc = val - mu;
    float vr = wredsum(xc * xc) * 0.015625f;
    float z = xc * (1.0f / sqrtf(vr + 1e-5f)) * lnG + lnB;
    zfmL[tid] = z;
    float zo = __shfl_xor(z, 1);
    if ((tid & 1) == 0) {
      h2 hp = {(_Float16)z, (_Float16)zo};
      zh16L[tid >> 1] = __builtin_bit_cast(unsigned, hp);
    }
    float s2 = wredsum(z * z);
    if (ln == 0) z2pL[wv] = s2;
  }
  __syncthreads();
  if (tid == 0) { float z2 = z2pL[0] + z2pL[1]; z2S = z2; szS = sqrtf(z2); }
  __syncthreads();

  int t = 0, it = 0;
  unsigned k = 1;
  for (;;) {
    const unsigned par = k & 1u;
    // ================= V: local full-codebook VQ (f16 approx) =================
    h2 zh[64];
#pragma unroll
    for (int j = 0; j < 16; ++j) {
      uint4 q = ((const uint4*)zh16L)[j];
      zh[4 * j + 0] = bch2(q.x); zh[4 * j + 1] = bch2(q.y);
      zh[4 * j + 2] = bch2(q.z); zh[4 * j + 3] = bch2(q.w);
    }
    const float z2 = z2S, sz = szS;
    float aV[16], eV[16];
    float lmin = 1e30f;
    for (int cc = 0; cc < 16; ++cc) {
      const int c = cc * 512 + tid;
      const uint4* ep = (const uint4*)(vqeH + ((size_t)c << 7));
      float d0 = 0.f, d1 = 0.f, d2a = 0.f, d3 = 0.f;
#pragma unroll
      for (int j = 0; j < 16; ++j) {
        uint4 q = ep[j];
        d0 = FDOT2(bch2(q.x), zh[4 * j + 0], d0);
        d1 = FDOT2(bch2(q.y), zh[4 * j + 1], d1);
        d2a = FDOT2(bch2(q.z), zh[4 * j + 2], d2a);
        d3 = FDOT2(bch2(q.w), zh[4 * j + 3], d3);
      }
      float dot = (d0 + d1) + (d2a + d3);
      float es = esqG[c];
      float a = (z2 - 2.0f * dot) + es;
      float e = fmaf(0.0015f * sz, sqrtf(es), 2e-3f);
      aV[cc] = a; eV[cc] = e;
      float ae = a + e;
      if (ae < lmin) lmin = ae;
    }
#pragma unroll
    for (int m = 32; m > 0; m >>= 1) {
      float o = __shfl_xor(lmin, m);
      if (o < lmin) lmin = o;
    }
    if (ln == 0) LredL[wv] = lmin;
    __syncthreads();
    float Lm = LredL[0];
#pragma unroll
    for (int w = 1; w < 8; ++w) if (LredL[w] < Lm) Lm = LredL[w];
#pragma unroll
    for (int cc = 0; cc < 16; ++cc)
      if (aV[cc] - eV[cc] <= Lm) {
        unsigned pos = atomicAdd(&candCountL, 1u) & 1023u;
        candCodeL[pos] = (unsigned)(cc * 512 + tid);
      }
    __syncthreads();
    const unsigned cnt = (candCountL < 1024u) ? candCountL : 1024u;
    // ---- exact f32 rescue (all-local: z in LDS, vqe cached) ----
    for (unsigned base = 0; base < cnt; base += 128u) {
      const unsigned eI = base + (unsigned)(tid >> 2);
      const int sub = tid & 3;
      const bool valid = eI < cnt;
      float dsum = 0.f;
      int code = 0;
      if (valid) {
        code = (int)candCodeL[eI];
        const float4* ep = (const float4*)(vqe + ((size_t)code << 7) + sub * 32);
#pragma unroll
        for (int j = 0; j < 8; ++j) {
          float4 e4 = ep[j];
          float4 zv = *(const float4*)&zfmL[sub * 32 + j * 4];
          dsum = fmaf(zv.x, e4.x, fmaf(zv.y, e4.y, fmaf(zv.z, e4.z, fmaf(zv.w, e4.w, dsum))));
        }
      }
      dsum += __shfl_xor(dsum, 1);
      dsum += __shfl_xor(dsum, 2);
      if (valid && sub == 0)
        koutL[eI] = packkey((z2 - 2.0f * dsum) + esqG[code], (unsigned)code);
    }
    __syncthreads();
    if (tid == 0) {
      u64 kk = koutL[0];
      for (unsigned j = 1; j < cnt; ++j) if (koutL[j] < kk) kk = koutL[j];
      iiS = (unsigned)kk & IDXM;
      st_coh64(&finalA[par * 128 + blk], kk | ((u64)k << 13));
      candCountL = 0u;
    }
    // ================= C-prep (hides finals skew) =================
    if (tid < 192) {
      const int h = tid >> 6, j = tid & 63;
      const float* wr = qWr + h * 4096 + j * 64;
      const float* wi = qWi + h * 4096 + j * 64;
      float da = 0.0f, db_ = 0.0f, dc2 = 0.0f, de = 0.0f;
#pragma unroll 4
      for (int d4 = 0; d4 < 64; d4 += 4) {
        float4 wrv = *(const float4*)&wr[d4];
        float4 wiv = *(const float4*)&wi[d4];
        float4 crv = *(const float4*)&zfmL[d4];
        float4 civ = *(const float4*)&zfmL[64 + d4];
        da = fmaf(crv.x, wrv.x, fmaf(crv.y, wrv.y, fmaf(crv.z, wrv.z, fmaf(crv.w, wrv.w, da))));
        db_ = fmaf(civ.x, wiv.x, fmaf(civ.y, wiv.y, fmaf(civ.z, wiv.z, fmaf(civ.w, wiv.w, db_))));
        dc2 = fmaf(civ.x, wrv.x, fmaf(civ.y, wrv.y, fmaf(civ.z, wrv.z, fmaf(civ.w, wrv.w, dc2))));
        de = fmaf(crv.x, wiv.x, fmaf(crv.y, wiv.y, fmaf(crv.z, wiv.z, fmaf(crv.w, wiv.w, de))));
      }
      float brv = qbr[h * 64 + j], biv = qbi[h * 64 + j];
      qkL[2 * h][j] = da + brv - db_ - biv;
      qkL[2 * h + 1][j] = dc2 + brv + de + biv;
    } else if (tid < 224) {
      const int s2 = tid - 192;
      float a2 = 0.0f;
      for (int d = 0; d < 64; ++d)
        a2 = fmaf(memLr[s2 * 65 + d], zfmL[d], fmaf(memLi[s2 * 65 + d], zfmL[64 + d], a2));
      simL[s2] = a2;
    } else if (tid < 227) {
      const int h = tid - 224;
      float a2 = ab[h];
      for (int k2 = 0; k2 < 128; ++k2) a2 = fmaf(zfmL[k2], arbWL[h * 128 + k2], a2);
      scalL[3 + h] = a2;
    }
    __syncthreads();
    if (tid < 64) {
      float p = fmaf(qkL[0][tid], qkL[2][tid], qkL[1][tid] * qkL[3][tid]);
      p = wredsum(p);
      if (tid == 0) scalL[0] = 1.0f / (1.0f + expf(-p));
    } else if (tid < 96) {
      const int s2 = tid - 64;
      float v = simL[s2];
      float m = v;
#pragma unroll
      for (int msk = 16; msk > 0; msk >>= 1) m = fmaxf(m, __shfl_xor(m, msk));
      float e = expf(v - m);
      float ss = e;
#pragma unroll
      for (int msk = 16; msk > 0; msk >>= 1) ss += __shfl_xor(ss, msk);
      attnL[s2] = e / ss;
    } else if (tid == 96) {
      float a0 = scalL[3], a1 = scalL[4], a2 = scalL[5];
      float m = fmaxf(a0, fmaxf(a1, a2));
      float e0 = expf(a0 - m), e1 = expf(a1 - m), e2 = expf(a2 - m);
      float ssum = e0 + e1 + e2;
      scalL[3] = e0 / ssum; scalL[4] = e1 / ssum; scalL[5] = e2 / ssum;
    }
    __syncthreads();
    if (tid < 128) {
      const int d = ln;
      const float* ml = (wv == 0) ? memLr : memLi;
      float a2 = 0.0f;
#pragma unroll 4
      for (int s2 = 0; s2 < 32; ++s2) a2 = fmaf(attnL[s2], ml[s2 * 65 + d], a2);
      if (wv == 0) mrL[d] = a2; else miL[d] = a2;
    }
    // ================= finals poll (parity buffer, tag == k) =================
    if (tid < 128) {
      const u64* fp = &finalA[par * 128 + tid];
      u64 v;
      while (true) {
        v = ld_coh64(fp);
        if (__all(((unsigned)(v >> 13) & 0x7FFFFu) == k)) break;
        __builtin_amdgcn_s_sleep(1);
      }
      key128L[tid] = v;
    }
    __syncthreads();
    // ---------- consensus (waves 0-1) || zq fetch + vq partials (waves 2-3) ----------
    const bool aoldb = ((actM[blk >> 6] >> (blk & 63)) & 1ull) != 0ull;
    if (tid < 128) {
      u64 key = key128L[tid];
      idxL[tid] = (unsigned)key & IDXM;
      float d2 = unpackd2(key);
      bool act_b = ((actM[tid >> 6] >> (tid & 63)) & 1ull) != 0ull;
      bool stop = (1.25f * 0.0078125f * d2) < hbias;
      u64 ball = __ballot(act_b && !stop);
      if (ln == 0) actN[tid >> 6] = ball;
    } else if (tid < 256) {
      const int d = tid - 128;
      float zq = vqe[((size_t)iiS << 7) + d];
      zqL[d] = zq;
      float df = zq - zfmL[d];
      float sm = wredsum(df * df);
      if (ln == 0) vqpL[wv - 2] = sm;
    }
    __syncthreads();
    const bool anyAct = (actN[0] | actN[1]) != 0ull;
    const bool mf = aoldb;
    if (tid < 2) actM[tid] = actN[tid];
    // ---------- candidate (stash cdr/cdi in mrL/miL for phase-diff) ----------
    if (tid < 64) {
      const int d = tid;
      float gate = scalL[0], g0 = scalL[3], g1 = scalL[4], g2 = scalL[5];
      float cr = zfmL[d], ci = zfmL[64 + d];
      float ur = fmaf(g0, qkL[4][d] * gate, fmaf(g1, mrL[d], g2 * zqL[d]));
      float ui = fmaf(g0, qkL[5][d] * gate, fmaf(g1, miL[d], g2 * zqL[64 + d]));
      float cdr = fmaf(0.4f, ur, 0.6f * cr);
      float cdi = fmaf(0.4f, ui, 0.6f * ci);
      mrL[d] = cdr; miL[d] = cdi;
      if (mf) { gwrowL[d] = cdr; gwrowL[64 + d] = cdi; }
    }
    __syncthreads();
    const bool newT = (!anyAct) || (it == MAXREC - 1);
    const bool finished = newT && (t == TT - 1);
    // ---------- commit t-advance ----------
    if (newT && !finished) {
      float pr = 0.0f;
      if (tid < 128) {
        pr = gwrowL[tid];
        outhB[((size_t)blk * TT + t) * 128 + tid] = f2bf(pr);
        float part = wredsum(pr * gtwv);
        if (ln == 0) wsumL[wv] = part;
      }
      __syncthreads();
      if (tid < 128) {
        int tok = x_seq[blk * TT + t + 1];
        float wg = 1.0f / (1.0f + expf(-(wsumL[0] + wsumL[1] + gtb0)));
        int slot = 31 - t;
        float* m = (tid < 64) ? &memLr[slot * 65 + tid] : &memLi[slot * 65 + (tid - 64)];
        *m = fmaf(wg, pr, (1.0f - wg) * (*m));
        gwrowL[tid] = fmaf(alpha, pr, onema * enc[((size_t)tok << 7) + tid]);
      }
      __syncthreads();
    }
    // ---------- LN -> z(k+1) (local only!) || entropy (waves 2-3) ----------
    if (!finished && tid < 128) {
      float val = gwrowL[tid];
      float mu = wredsum(val) * 0.015625f;
      float xc = val - mu;
      float vr = wredsum(xc * xc) * 0.015625f;
      float z = xc * (1.0f / sqrtf(vr + 1e-5f)) * lnG + lnB;
      zfmL[tid] = z;
      float zo = __shfl_xor(z, 1);
      if ((tid & 1) == 0) {
        h2 hp = {(_Float16)z, (_Float16)zo};
        zh16L[tid >> 1] = __builtin_bit_cast(unsigned, hp);
      }
      float s2 = wredsum(z * z);
      if (ln == 0) z2pL[wv] = s2;
    } else if (tid >= 128 && tid < 256) {
      const int r = tid - 128;
      unsigned my = idxL[r];
      int c = 0;
#pragma unroll
      for (int j4 = 0; j4 < 32; ++j4) {
        uint4 q = *(const uint4*)&idxL[j4 * 4];
        c += (q.x == my) + (q.y == my) + (q.z == my) + (q.w == my);
      }
      float term = -0.0078125f * logf((float)c * 0.0078125f + 1e-10f);
      term = wredsum(term);
      if (ln == 0) entpL[wv - 2] = term;
    }
    __syncthreads();
    // ---------- phase-diff (wave 0) || z2 combine ----------
    if (tid < 64) {
      const int d = tid;
      float ang = atan2f(miL[d], mrL[d]);
      float df = fabsf(ang - pangL[d]);
      df = fminf(df, TWO_PI_F - df);
      pangL[d] = ang;
      float dm = wredsum(df) * 0.015625f;
      if (d == 0) dmeanS = dm;
    } else if (tid == 64) {
      float z2 = z2pL[0] + z2pL[1];
      z2S = z2; szS = sqrtf(z2);
    }
    __syncthreads();
    if (tid == 0) {
      float aold = mf ? 1.0f : 0.0f;
      accL[3] += aold * dmeanS;
      accL[2] += aold * 0.01f;
      if (mf) {
        accL[0] = 1.25f * (vqpL[0] + vqpL[1]) * 0.0078125f;
        accL[1] = entpL[0] + entpL[1];
        dout[(size_t)LOGN + 4 + (size_t)blk * TT + t] = (float)iiS;
      }
    }
    if (newT && !finished) {
      if (tid < 64) pangL[tid] = atan2f(gwrowL[64 + tid], gwrowL[tid]);
      if (tid < 4) { totL[tid] += accL[tid]; accL[tid] = 0.0f; }
      if (tid < 2) actM[tid] = ~0ull;
    }
    __syncthreads();
    if (finished) break;
    if (newT) { t++; it = 0; } else { it++; }
    k++;
  }

  // epilogue: final gw (cand-updated) + stats flush
  if (tid < 128) outhB[((size_t)blk * TT + (TT - 1)) * 128 + tid] = f2bf(gwrowL[tid]);
  if (tid < 4) rst[blk * 4 + tid] = totL[tid] + accL[tid];
}

// ================= MFMA decoder: 4096x8192x128 bf16 -> f32 =================
__global__ __launch_bounds__(256) void k_dec(
    const float* __restrict__ dbv, float* __restrict__ dout,
    const char* __restrict__ ws)
{
  const unsigned short* outhB = (const unsigned short*)(ws + OFF_OUTHB);
  const unsigned short* dWb = (const unsigned short*)(ws + OFF_WB);
  const float* rst = (const float*)(ws + OFF_RST);
  const int tid = threadIdx.x;
  if (blockIdx.x == 0 && tid < 4) {
    float s = 0.0f;
    for (int r = 0; r < 128; ++r) s += rst[r * 4 + tid];
    dout[(size_t)LOGN + tid] = s * (1.0f / 4096.0f);
  }
  const int w = tid >> 6, l = tid & 63;
  const int bm = blockIdx.x & 63;
  const int bn = blockIdx.x >> 6;
  const int ar = l & 15, kg = l >> 4;
  const int m_base = bm * 64;
  const int n_base = bn * 256 + w * 64;
  f32x4 acc[4][4];
#pragma unroll
  for (int mt = 0; mt < 4; ++mt)
#pragma unroll
    for (int nt = 0; nt < 4; ++nt) acc[mt][nt] = (f32x4){0.f, 0.f, 0.f, 0.f};
#pragma unroll
  for (int kc = 0; kc < 4; ++kc) {
    const int ko = kc * 32 + kg * 8;
    bf16x8 a[4], b[4];
#pragma unroll
    for (int mt = 0; mt < 4; ++mt)
      a[mt] = *(const bf16x8*)(outhB + (size_t)(m_base + mt * 16 + ar) * 128 + ko);
#pragma unroll
    for (int nt = 0; nt < 4; ++nt)
      b[nt] = *(const bf16x8*)(dWb + (size_t)(n_base + nt * 16 + ar) * 128 + ko);
#pragma unroll
    for (int mt = 0; mt < 4; ++mt)
#pragma unroll
      for (int nt = 0; nt < 4; ++nt)
        acc[mt][nt] = __builtin_amdgcn_mfma_f32_16x16x32_bf16(a[mt], b[nt], acc[mt][nt], 0, 0, 0);
  }
#pragma unroll
  for (int nt = 0; nt < 4; ++nt) {
    const int n = n_base + nt * 16 + ar;
    const float bv = dbv[n];
#pragma unroll
    for (int mt = 0; mt < 4; ++mt) {
#pragma unroll
      for (int rr = 0; rr < 4; ++rr) {
        const int m = m_base + mt * 16 + kg * 4 + rr;
        dout[(size_t)m * 8192 + n] = acc[mt][nt][rr] + bv;
      }
    }
  }
}

extern "C" void kernel_launch(void* const* d_in, const int* in_sizes, int n_in,
                              void* d_out, int out_size, void* d_ws, size_t ws_size,
                              hipStream_t stream) {
  (void)in_sizes; (void)n_in; (void)out_size; (void)ws_size;
  const int*   x_seq = (const int*)d_in[0];
  const float* enc = (const float*)d_in[1];
  const float* vq  = (const float*)d_in[2];
  const float* nrg = (const float*)d_in[3];
  const float* nrb = (const float*)d_in[4];
  const float* nig = (const float*)d_in[5];
  const float* nib = (const float*)d_in[6];
  const float* qWr = (const float*)d_in[7];
  const float* qbr = (const float*)d_in[8];
  const float* qWi = (const float*)d_in[9];
  const float* qbi = (const float*)d_in[10];
  const float* gtw = (const float*)d_in[11];
  const float* gtb = (const float*)d_in[12];
  const float* aW  = (const float*)d_in[13];
  const float* ab  = (const float*)d_in[14];
  const float* dW  = (const float*)d_in[15];
  const float* db  = (const float*)d_in[16];
  const float* hb  = (const float*)d_in[17];
  const float* ig  = (const float*)d_in[18];
  char* ws = (char*)d_ws;
  float* out = (float*)d_out;
  hipLaunchKernelGGL(sacrsn_init, dim3(1), dim3(256), 0, stream, ws);
  hipLaunchKernelGGL(k_prepv, dim3(1024), dim3(256), 0, stream, vq, ws);
  hipLaunchKernelGGL(sacrsn_main, dim3(NBLK), dim3(NTHR), 0, stream,
                     x_seq, enc, vq, nrg, nrb, nig, nib, qWr, qbr, qWi, qbi,
                     gtw, gtb, aW, ab, hb, ig, out, ws);
  hipLaunchKernelGGL(k_prepd, dim3(1024), dim3(256), 0, stream, dW, ws);
  hipLaunchKernelGGL(k_dec, dim3(2048), dim3(256), 0, stream, db, out, ws);
}

// Round 16
// 3016.290 us; speedup vs baseline: 1.0037x; 1.0037x over previous
//
#include <hip/hip_runtime.h>
#include <math.h>

#define TT 32
#define MAXREC 8
#define NBLK 128
#define NTHR 512

// workspace byte offsets
#define OFF_FINAL  0u          // 2 x 128 u64 tagged finals (parity buffers) = 2048
#define OFF_ESQ    4096u       // 8192 f32 exact |e|^2 = 32768
#define OFF_RST    36864u      // 128*4 f32
#define OFF_OUTHB  40960u      // 4096*128 bf16 = 1048576
#define OFF_WB     1089536u    // 2 MB: vqeH f16 (main) then dWb bf16 (k_dec)

#define IDXM 0x1FFFu
#define LOGN 33554432u        // 128*32*8192
#define TWO_PI_F 6.283185307179586f

typedef float f32x4 __attribute__((ext_vector_type(4)));
typedef short bf16x8 __attribute__((ext_vector_type(8)));
typedef _Float16 h2 __attribute__((ext_vector_type(2)));
typedef unsigned long long u64;

__device__ __forceinline__ float wredsum(float v) {
#pragma unroll
  for (int m = 32; m > 0; m >>= 1) v += __shfl_xor(v, m);
  return v;
}
// monotone float->u32 + 13-bit idx: u64-min == (min dist, then min idx)
__device__ __forceinline__ u64 packkey(float d, unsigned c) {
  unsigned u = __float_as_uint(d);
  u = (u & 0x80000000u) ? ~u : (u | 0x80000000u);
  return ((u64)u << 32) | c;
}
__device__ __forceinline__ float unpackd2(u64 key) {
  unsigned hi = (unsigned)(key >> 32);
  unsigned orig = (hi & 0x80000000u) ? (hi & 0x7fffffffu) : ~hi;
  return __uint_as_float(orig);
}
__device__ __forceinline__ unsigned short f2bf(float f) {
  unsigned u = __float_as_uint(f);
  unsigned r = (u >> 16) & 1u;
  u += 0x7fffu + r;
  return (unsigned short)(u >> 16);
}
__device__ __forceinline__ h2 bch2(unsigned u) { return __builtin_bit_cast(h2, u); }

#if __has_builtin(__builtin_amdgcn_fdot2)
#define FDOT2(a, b, c) __builtin_amdgcn_fdot2((a), (b), (c), false)
#else
#define FDOT2(a, b, c) fmaf((float)(a).x, (float)(b).x, fmaf((float)(a).y, (float)(b).y, (c)))
#endif

// ---- coherent (cross-XCD) accesses: finals only ----
__device__ __forceinline__ u64 ld_coh64(const u64* p) {
  u64 v;
  asm volatile("global_load_dwordx2 %0, %1, off sc0 sc1\n\ts_waitcnt vmcnt(0)"
               : "=&v"(v) : "v"(p) : "memory");
  return v;
}
__device__ __forceinline__ void st_coh64(u64* p, u64 v) {
  asm volatile("global_store_dwordx2 %0, %1, off sc0 sc1\n\ts_waitcnt vmcnt(0)"
               :: "v"(p), "v"(v) : "memory");
}

__global__ __launch_bounds__(256) void sacrsn_init(char* __restrict__ ws) {
  u64* fin = (u64*)(ws + OFF_FINAL);
  fin[threadIdx.x] = 0ull;   // 256 = both parity buffers
}

// vq_emb f32 -> f16 (WB) + exact esq
__global__ __launch_bounds__(256) void k_prepv(const float* __restrict__ vqe,
                                               char* __restrict__ ws) {
  _Float16* vqeH = (_Float16*)(ws + OFF_WB);
  float* esqG = (float*)(ws + OFF_ESQ);
  const int i = (blockIdx.x * 256 + threadIdx.x) * 4;
  float4 v = *(const float4*)(vqe + i);
  h2 lo = {(_Float16)v.x, (_Float16)v.y};
  h2 hi = {(_Float16)v.z, (_Float16)v.w};
  *(h2*)(vqeH + i) = lo;
  *(h2*)(vqeH + i + 2) = hi;
  if (blockIdx.x < 32) {
    const int c = blockIdx.x * 256 + threadIdx.x;
    const float4* e = (const float4*)(vqe + ((size_t)c << 7));
    float s = 0.f;
#pragma unroll 8
    for (int k4 = 0; k4 < 32; ++k4) {
      float4 q = e[k4];
      s = fmaf(q.x, q.x, fmaf(q.y, q.y, fmaf(q.z, q.z, fmaf(q.w, q.w, s))));
    }
    esqG[c] = s;
  }
}

// dec_W f32 -> bf16 (WB), runs AFTER main
__global__ __launch_bounds__(256) void k_prepd(const float* __restrict__ dW,
                                               char* __restrict__ ws) {
  unsigned short* dWb = (unsigned short*)(ws + OFF_WB);
  const int i = (blockIdx.x * 256 + threadIdx.x) * 4;
  float4 v = *(const float4*)(dW + i);
  ushort4 o;
  o.x = f2bf(v.x); o.y = f2bf(v.y); o.z = f2bf(v.z); o.w = f2bf(v.w);
  *(ushort4*)(dWb + i) = o;
}

__global__ __launch_bounds__(NTHR) void sacrsn_main(
    const int* __restrict__ x_seq, const float* __restrict__ enc,
    const float* __restrict__ vqe,
    const float* __restrict__ nrg, const float* __restrict__ nrb,
    const float* __restrict__ nig, const float* __restrict__ nib,
    const float* __restrict__ qWr, const float* __restrict__ qbr,
    const float* __restrict__ qWi, const float* __restrict__ qbi,
    const float* __restrict__ gtw, const float* __restrict__ gtb,
    const float* __restrict__ aW, const float* __restrict__ ab,
    const float* __restrict__ hbp, const float* __restrict__ igp,
    float* __restrict__ dout, char* __restrict__ ws)
{
  u64* finalA = (u64*)(ws + OFF_FINAL);                 // [parity][128]
  const float* esqG = (const float*)(ws + OFF_ESQ);
  const _Float16* vqeH = (const _Float16*)(ws + OFF_WB);
  unsigned short* outhB = (unsigned short*)(ws + OFF_OUTHB);
  float* rst = (float*)(ws + OFF_RST);

  const int tid = threadIdx.x;
  const int wv = tid >> 6, ln = tid & 63;
  const int blk = blockIdx.x;                           // = row

  // ---- LDS ----
  __shared__ float memLr[32 * 65];
  __shared__ float memLi[32 * 65];
  __shared__ __align__(16) float zfmL[128];
  __shared__ __align__(16) unsigned zh16L[64];          // z as packed f16 pairs
  __shared__ float amlL[16 * NTHR];                     // a-e per (cc,thread): LDS, not scratch!
  __shared__ float gwrowL[128], pangL[64], zqL[128];
  __shared__ float qkL[6][64], simL[32], attnL[32], mrL[64], miL[64];
  __shared__ unsigned idxL[128] __attribute__((aligned(16)));
  __shared__ u64 key128L[128];
  __shared__ float arbWL[3 * 128];
  __shared__ float scalL[8], entpL[2], vqpL[2], wsumL[2], z2pL[2];
  __shared__ float accL[4], totL[4];
  __shared__ float dmeanS, z2S, szS;
  __shared__ unsigned iiS;
  __shared__ u64 actM[2], actN[2];
  __shared__ float LredL[8];
  __shared__ unsigned candCodeL[1024];
  __shared__ unsigned candCountL;
  __shared__ u64 koutL[1024];

  const float alpha = 1.0f / (1.0f + expf(-igp[0]));
  const float onema = 1.0f - alpha;
  const float hbias = log1pf(expf(hbp[0]));
  const float gtb0 = gtb[0];

  float lnG = 0.0f, lnB = 0.0f, gtwv = 0.0f;
  if (tid < 64) { lnG = nrg[tid]; lnB = nrb[tid]; }
  else if (tid < 128) { lnG = nig[tid - 64]; lnB = nib[tid - 64]; }
  if (tid < 128) gtwv = gtw[tid];
  for (int i = tid; i < 32 * 65; i += NTHR) { memLr[i] = 0.0f; memLi[i] = 0.0f; }
  if (tid < 4) { totL[tid] = 0.0f; accL[tid] = 0.0f; }
  if (tid < 2) actM[tid] = ~0ull;
  if (tid == 0) candCountL = 0u;
  for (int i = tid; i < 384; i += NTHR) arbWL[i] = aW[i];
  {
    int tok = x_seq[blk * TT];
    if (tid < 128) gwrowL[tid] = onema * enc[((size_t)tok << 7) + tid];
  }
  __syncthreads();
  if (tid < 64) pangL[tid] = atan2f(gwrowL[64 + tid], gwrowL[tid]);
  if (tid < 128) {
    float val = gwrowL[tid];
    float mu = wredsum(val) * 0.015625f;
    float xc = val - mu;
    float vr = wredsum(xc * xc) * 0.015625f;
    float z = xc * (1.0f / sqrtf(vr + 1e-5f)) * lnG + lnB;
    zfmL[tid] = z;
    float zo = __shfl_xor(z, 1);
    if ((tid & 1) == 0) {
      h2 hp = {(_Float16)z, (_Float16)zo};
      zh16L[tid >> 1] = __builtin_bit_cast(unsigned, hp);
    }
    float s2 = wredsum(z * z);
    if (ln == 0) z2pL[wv] = s2;
  }
  __syncthreads();
  if (tid == 0) { float z2 = z2pL[0] + z2pL[1]; z2S = z2; szS = sqrtf(z2); }
  __syncthreads();

  int t = 0, it = 0;
  unsigned k = 1;
  for (;;) {
    const unsigned par = k & 1u;
    // ================= V: local full-codebook VQ (f16 approx, LDS-staged a-e) =================
    h2 zh[64];
#pragma unroll
    for (int j = 0; j < 16; ++j) {
      uint4 q = ((const uint4*)zh16L)[j];
      zh[4 * j + 0] = bch2(q.x); zh[4 * j + 1] = bch2(q.y);
      zh[4 * j + 2] = bch2(q.z); zh[4 * j + 3] = bch2(q.w);
    }
    const float z2 = z2S, sz = szS;
    float lmin = 1e30f;
    for (int cc = 0; cc < 16; ++cc) {
      const int c = cc * NTHR + tid;
      const uint4* ep = (const uint4*)(vqeH + ((size_t)c << 7));
      float d0 = 0.f, d1 = 0.f, d2a = 0.f, d3 = 0.f;
#pragma unroll
      for (int j = 0; j < 16; ++j) {
        uint4 q = ep[j];
        d0 = FDOT2(bch2(q.x), zh[4 * j + 0], d0);
        d1 = FDOT2(bch2(q.y), zh[4 * j + 1], d1);
        d2a = FDOT2(bch2(q.z), zh[4 * j + 2], d2a);
        d3 = FDOT2(bch2(q.w), zh[4 * j + 3], d3);
      }
      float dot = (d0 + d1) + (d2a + d3);
      float es = esqG[c];
      float a = (z2 - 2.0f * dot) + es;
      float e = fmaf(0.0015f * sz, sqrtf(es), 2e-3f);
      amlL[cc * NTHR + tid] = a - e;      // LDS (dynamic cc ok) — no scratch
      float ae = a + e;
      if (ae < lmin) lmin = ae;
    }
#pragma unroll
    for (int m = 32; m > 0; m >>= 1) {
      float o = __shfl_xor(lmin, m);
      if (o < lmin) lmin = o;
    }
    if (ln == 0) LredL[wv] = lmin;
    __syncthreads();
    float Lm = LredL[0];
#pragma unroll
    for (int w = 1; w < 8; ++w) if (LredL[w] < Lm) Lm = LredL[w];
    for (int cc = 0; cc < 16; ++cc)
      if (amlL[cc * NTHR + tid] <= Lm) {
        unsigned pos = atomicAdd(&candCountL, 1u) & 1023u;
        candCodeL[pos] = (unsigned)(cc * NTHR + tid);
      }
    __syncthreads();
    const unsigned cnt = (candCountL < 1024u) ? candCountL : 1024u;
    // ---- exact f32 rescue (all-local: z in LDS, vqe cached) ----
    for (unsigned base = 0; base < cnt; base += 128u) {
      const unsigned eI = base + (unsigned)(tid >> 2);
      const int sub = tid & 3;
      const bool valid = eI < cnt;
      float dsum = 0.f;
      int code = 0;
      if (valid) {
        code = (int)candCodeL[eI];
        const float4* ep = (const float4*)(vqe + ((size_t)code << 7) + sub * 32);
#pragma unroll
        for (int j = 0; j < 8; ++j) {
          float4 e4 = ep[j];
          float4 zv = *(const float4*)&zfmL[sub * 32 + j * 4];
          dsum = fmaf(zv.x, e4.x, fmaf(zv.y, e4.y, fmaf(zv.z, e4.z, fmaf(zv.w, e4.w, dsum))));
        }
      }
      dsum += __shfl_xor(dsum, 1);
      dsum += __shfl_xor(dsum, 2);
      if (valid && sub == 0)
        koutL[eI] = packkey((z2 - 2.0f * dsum) + esqG[code], (unsigned)code);
    }
    __syncthreads();
    if (tid == 0) {
      u64 kk = koutL[0];
      for (unsigned j = 1; j < cnt; ++j) if (koutL[j] < kk) kk = koutL[j];
      iiS = (unsigned)kk & IDXM;
      st_coh64(&finalA[par * 128 + blk], kk | ((u64)k << 13));
      candCountL = 0u;
    }
    // ================= C-prep (hides finals skew) =================
    if (tid < 192) {
      const int h = tid >> 6, j = tid & 63;
      const float* wr = qWr + h * 4096 + j * 64;
      const float* wi = qWi + h * 4096 + j * 64;
      float da = 0.0f, db_ = 0.0f, dc2 = 0.0f, de = 0.0f;
#pragma unroll 4
      for (int d4 = 0; d4 < 64; d4 += 4) {
        float4 wrv = *(const float4*)&wr[d4];
        float4 wiv = *(const float4*)&wi[d4];
        float4 crv = *(const float4*)&zfmL[d4];
        float4 civ = *(const float4*)&zfmL[64 + d4];
        da = fmaf(crv.x, wrv.x, fmaf(crv.y, wrv.y, fmaf(crv.z, wrv.z, fmaf(crv.w, wrv.w, da))));
        db_ = fmaf(civ.x, wiv.x, fmaf(civ.y, wiv.y, fmaf(civ.z, wiv.z, fmaf(civ.w, wiv.w, db_))));
        dc2 = fmaf(civ.x, wrv.x, fmaf(civ.y, wrv.y, fmaf(civ.z, wrv.z, fmaf(civ.w, wrv.w, dc2))));
        de = fmaf(crv.x, wiv.x, fmaf(crv.y, wiv.y, fmaf(crv.z, wiv.z, fmaf(crv.w, wiv.w, de))));
      }
      float brv = qbr[h * 64 + j], biv = qbi[h * 64 + j];
      qkL[2 * h][j] = da + brv - db_ - biv;
      qkL[2 * h + 1][j] = dc2 + brv + de + biv;
    } else if (tid < 224) {
      const int s2 = tid - 192;
      float a2 = 0.0f;
      for (int d = 0; d < 64; ++d)
        a2 = fmaf(memLr[s2 * 65 + d], zfmL[d], fmaf(memLi[s2 * 65 + d], zfmL[64 + d], a2));
      simL[s2] = a2;
    } else if (tid < 227) {
      const int h = tid - 224;
      float a2 = ab[h];
      for (int k2 = 0; k2 < 128; ++k2) a2 = fmaf(zfmL[k2], arbWL[h * 128 + k2], a2);
      scalL[3 + h] = a2;
    }
    __syncthreads();
    if (tid < 64) {
      float p = fmaf(qkL[0][tid], qkL[2][tid], qkL[1][tid] * qkL[3][tid]);
      p = wredsum(p);
      if (tid == 0) scalL[0] = 1.0f / (1.0f + expf(-p));
    } else if (tid < 96) {
      const int s2 = tid - 64;
      float v = simL[s2];
      float m = v;
#pragma unroll
      for (int msk = 16; msk > 0; msk >>= 1) m = fmaxf(m, __shfl_xor(m, msk));
      float e = expf(v - m);
      float ss = e;
#pragma unroll
      for (int msk = 16; msk > 0; msk >>= 1) ss += __shfl_xor(ss, msk);
      attnL[s2] = e / ss;
    } else if (tid == 96) {
      float a0 = scalL[3], a1 = scalL[4], a2 = scalL[5];
      float m = fmaxf(a0, fmaxf(a1, a2));
      float e0 = expf(a0 - m), e1 = expf(a1 - m), e2 = expf(a2 - m);
      float ssum = e0 + e1 + e2;
      scalL[3] = e0 / ssum; scalL[4] = e1 / ssum; scalL[5] = e2 / ssum;
    }
    __syncthreads();
    if (tid < 128) {
      const int d = ln;
      const float* ml = (wv == 0) ? memLr : memLi;
      float a2 = 0.0f;
#pragma unroll 4
      for (int s2 = 0; s2 < 32; ++s2) a2 = fmaf(attnL[s2], ml[s2 * 65 + d], a2);
      if (wv == 0) mrL[d] = a2; else miL[d] = a2;
    }
    // ================= finals poll (parity buffer, tag == k) =================
    if (tid < 128) {
      const u64* fp = &finalA[par * 128 + tid];
      u64 v;
      while (true) {
        v = ld_coh64(fp);
        if (__all(((unsigned)(v >> 13) & 0x7FFFFu) == k)) break;
        __builtin_amdgcn_s_sleep(1);
      }
      key128L[tid] = v;
    }
    __syncthreads();
    // ---------- consensus (waves 0-1) || zq fetch + vq partials (waves 2-3) ----------
    const bool aoldb = ((actM[blk >> 6] >> (blk & 63)) & 1ull) != 0ull;
    if (tid < 128) {
      u64 key = key128L[tid];
      idxL[tid] = (unsigned)key & IDXM;
      float d2 = unpackd2(key);
      bool act_b = ((actM[tid >> 6] >> (tid & 63)) & 1ull) != 0ull;
      bool stop = (1.25f * 0.0078125f * d2) < hbias;
      u64 ball = __ballot(act_b && !stop);
      if (ln == 0) actN[tid >> 6] = ball;
    } else if (tid < 256) {
      const int d = tid - 128;
      float zq = vqe[((size_t)iiS << 7) + d];
      zqL[d] = zq;
      float df = zq - zfmL[d];
      float sm = wredsum(df * df);
      if (ln == 0) vqpL[wv - 2] = sm;
    }
    __syncthreads();
    const bool anyAct = (actN[0] | actN[1]) != 0ull;
    const bool mf = aoldb;
    if (tid < 2) actM[tid] = actN[tid];
    // ---------- candidate (stash cdr/cdi in mrL/miL for phase-diff) ----------
    if (tid < 64) {
      const int d = tid;
      float gate = scalL[0], g0 = scalL[3], g1 = scalL[4], g2 = scalL[5];
      float cr = zfmL[d], ci = zfmL[64 + d];
      float ur = fmaf(g0, qkL[4][d] * gate, fmaf(g1, mrL[d], g2 * zqL[d]));
      float ui = fmaf(g0, qkL[5][d] * gate, fmaf(g1, miL[d], g2 * zqL[64 + d]));
      float cdr = fmaf(0.4f, ur, 0.6f * cr);
      float cdi = fmaf(0.4f, ui, 0.6f * ci);
      mrL[d] = cdr; miL[d] = cdi;
      if (mf) { gwrowL[d] = cdr; gwrowL[64 + d] = cdi; }
    }
    __syncthreads();
    const bool newT = (!anyAct) || (it == MAXREC - 1);
    const bool finished = newT && (t == TT - 1);
    // ---------- commit t-advance ----------
    if (newT && !finished) {
      float pr = 0.0f;
      if (tid < 128) {
        pr = gwrowL[tid];
        outhB[((size_t)blk * TT + t) * 128 + tid] = f2bf(pr);
        float part = wredsum(pr * gtwv);
        if (ln == 0) wsumL[wv] = part;
      }
      __syncthreads();
      if (tid < 128) {
        int tok = x_seq[blk * TT + t + 1];
        float wg = 1.0f / (1.0f + expf(-(wsumL[0] + wsumL[1] + gtb0)));
        int slot = 31 - t;
        float* m = (tid < 64) ? &memLr[slot * 65 + tid] : &memLi[slot * 65 + (tid - 64)];
        *m = fmaf(wg, pr, (1.0f - wg) * (*m));
        gwrowL[tid] = fmaf(alpha, pr, onema * enc[((size_t)tok << 7) + tid]);
      }
      __syncthreads();
    }
    // ---------- LN -> z(k+1) (local only!) || entropy (waves 2-3) ----------
    if (!finished && tid < 128) {
      float val = gwrowL[tid];
      float mu = wredsum(val) * 0.015625f;
      float xc = val - mu;
      float vr = wredsum(xc * xc) * 0.015625f;
      float z = xc * (1.0f / sqrtf(vr + 1e-5f)) * lnG + lnB;
      zfmL[tid] = z;
      float zo = __shfl_xor(z, 1);
      if ((tid & 1) == 0) {
        h2 hp = {(_Float16)z, (_Float16)zo};
        zh16L[tid >> 1] = __builtin_bit_cast(unsigned, hp);
      }
      float s2 = wredsum(z * z);
      if (ln == 0) z2pL[wv] = s2;
    } else if (tid >= 128 && tid < 256) {
      const int r = tid - 128;
      unsigned my = idxL[r];
      int c = 0;
#pragma unroll
      for (int j4 = 0; j4 < 32; ++j4) {
        uint4 q = *(const uint4*)&idxL[j4 * 4];
        c += (q.x == my) + (q.y == my) + (q.z == my) + (q.w == my);
      }
      float term = -0.0078125f * logf((float)c * 0.0078125f + 1e-10f);
      term = wredsum(term);
      if (ln == 0) entpL[wv - 2] = term;
    }
    __syncthreads();
    // ---------- phase-diff (wave 0) || z2 combine ----------
    if (tid < 64) {
      const int d = tid;
      float ang = atan2f(miL[d], mrL[d]);
      float df = fabsf(ang - pangL[d]);
      df = fminf(df, TWO_PI_F - df);
      pangL[d] = ang;
      float dm = wredsum(df) * 0.015625f;
      if (d == 0) dmeanS = dm;
    } else if (tid == 64) {
      float z2 = z2pL[0] + z2pL[1];
      z2S = z2; szS = sqrtf(z2);
    }
    __syncthreads();
    if (tid == 0) {
      float aold = mf ? 1.0f : 0.0f;
      accL[3] += aold * dmeanS;
      accL[2] += aold * 0.01f;
      if (mf) {
        accL[0] = 1.25f * (vqpL[0] + vqpL[1]) * 0.0078125f;
        accL[1] = entpL[0] + entpL[1];
        dout[(size_t)LOGN + 4 + (size_t)blk * TT + t] = (float)iiS;
      }
    }
    if (newT && !finished) {
      if (tid < 64) pangL[tid] = atan2f(gwrowL[64 + tid], gwrowL[tid]);
      if (tid < 4) { totL[tid] += accL[tid]; accL[tid] = 0.0f; }
      if (tid < 2) actM[tid] = ~0ull;
    }
    __syncthreads();
    if (finished) break;
    if (newT) { t++; it = 0; } else { it++; }
    k++;
  }

  // epilogue: final gw (cand-updated) + stats flush
  if (tid < 128) outhB[((size_t)blk * TT + (TT - 1)) * 128 + tid] = f2bf(gwrowL[tid]);
  if (tid < 4) rst[blk * 4 + tid] = totL[tid] + accL[tid];
}

// ================= MFMA decoder: 4096x8192x128 bf16 -> f32 =================
__global__ __launch_bounds__(256) void k_dec(
    const float* __restrict__ dbv, float* __restrict__ dout,
    const char* __restrict__ ws)
{
  const unsigned short* outhB = (const unsigned short*)(ws + OFF_OUTHB);
  const unsigned short* dWb = (const unsigned short*)(ws + OFF_WB);
  const float* rst = (const float*)(ws + OFF_RST);
  const int tid = threadIdx.x;
  if (blockIdx.x == 0 && tid < 4) {
    float s = 0.0f;
    for (int r = 0; r < 128; ++r) s += rst[r * 4 + tid];
    dout[(size_t)LOGN + tid] = s * (1.0f / 4096.0f);
  }
  const int w = tid >> 6, l = tid & 63;
  const int bm = blockIdx.x & 63;
  const int bn = blockIdx.x >> 6;
  const int ar = l & 15, kg = l >> 4;
  const int m_base = bm * 64;
  const int n_base = bn * 256 + w * 64;
  f32x4 acc[4][4];
#pragma unroll
  for (int mt = 0; mt < 4; ++mt)
#pragma unroll
    for (int nt = 0; nt < 4; ++nt) acc[mt][nt] = (f32x4){0.f, 0.f, 0.f, 0.f};
#pragma unroll
  for (int kc = 0; kc < 4; ++kc) {
    const int ko = kc * 32 + kg * 8;
    bf16x8 a[4], b[4];
#pragma unroll
    for (int mt = 0; mt < 4; ++mt)
      a[mt] = *(const bf16x8*)(outhB + (size_t)(m_base + mt * 16 + ar) * 128 + ko);
#pragma unroll
    for (int nt = 0; nt < 4; ++nt)
      b[nt] = *(const bf16x8*)(dWb + (size_t)(n_base + nt * 16 + ar) * 128 + ko);
#pragma unroll
    for (int mt = 0; mt < 4; ++mt)
#pragma unroll
      for (int nt = 0; nt < 4; ++nt)
        acc[mt][nt] = __builtin_amdgcn_mfma_f32_16x16x32_bf16(a[mt], b[nt], acc[mt][nt], 0, 0, 0);
  }
#pragma unroll
  for (int nt = 0; nt < 4; ++nt) {
    const int n = n_base + nt * 16 + ar;
    const float bv = dbv[n];
#pragma unroll
    for (int mt = 0; mt < 4; ++mt) {
#pragma unroll
      for (int rr = 0; rr < 4; ++rr) {
        const int m = m_base + mt * 16 + kg * 4 + rr;
        dout[(size_t)m * 8192 + n] = acc[mt][nt][rr] + bv;
      }
    }
  }
}

extern "C" void kernel_launch(void* const* d_in, const int* in_sizes, int n_in,
                              void* d_out, int out_size, void* d_ws, size_t ws_size,
                              hipStream_t stream) {
  (void)in_sizes; (void)n_in; (void)out_size; (void)ws_size;
  const int*   x_seq = (const int*)d_in[0];
  const float* enc = (const float*)d_in[1];
  const float* vq  = (const float*)d_in[2];
  const float* nrg = (const float*)d_in[3];
  const float* nrb = (const float*)d_in[4];
  const float* nig = (const float*)d_in[5];
  const float* nib = (const float*)d_in[6];
  const float* qWr = (const float*)d_in[7];
  const float* qbr = (const float*)d_in[8];
  const float* qWi = (const float*)d_in[9];
  const float* qbi = (const float*)d_in[10];
  const float* gtw = (const float*)d_in[11];
  const float* gtb = (const float*)d_in[12];
  const float* aW  = (const float*)d_in[13];
  const float* ab  = (const float*)d_in[14];
  const float* dW  = (const float*)d_in[15];
  const float* db  = (const float*)d_in[16];
  const float* hb  = (const float*)d_in[17];
  const float* ig  = (const float*)d_in[18];
  char* ws = (char*)d_ws;
  float* out = (float*)d_out;
  hipLaunchKernelGGL(sacrsn_init, dim3(1), dim3(256), 0, stream, ws);
  hipLaunchKernelGGL(k_prepv, dim3(1024), dim3(256), 0, stream, vq, ws);
  hipLaunchKernelGGL(sacrsn_main, dim3(NBLK), dim3(NTHR), 0, stream,
                     x_seq, enc, vq, nrg, nrb, nig, nib, qWr, qbr, qWi, qbi,
                     gtw, gtb, aW, ab, hb, ig, out, ws);
  hipLaunchKernelGGL(k_prepd, dim3(1024), dim3(256), 0, stream, dW, ws);
  hipLaunchKernelGGL(k_dec, dim3(2048), dim3(256), 0, stream, db, out, ws);
}